// Round 3
// baseline (438.372 us; speedup 1.0000x reference)
//
#include <hip/hip_runtime.h>
#include <stdint.h>

#define H 512
#define W 512
#define HW (H * W)
#define NIMG 128
#define AX 26214
#define NB 8192
#define CAP 12288
#define KS 3277   // ~AX/8 (sampled rank, 32768 sampled positions * 0.1)
#define KM 240    // ~4.4 sigma bracket margin
#define SMEM_WORDS (NB + CAP + 512 + 8)
#define SMEM_BYTES (SMEM_WORDS * 4)

__device__ __forceinline__ float4 f4zero() { return make_float4(0.f, 0.f, 0.f, 0.f); }

// Find bin b such that suffix_excl(b) < K <= suffix_excl(b) + hist[b]
// (rank K from the top / highest bins). Block = 1024 thr; tid<512 own 16 bins.
__device__ __forceinline__ void block_select(uint32_t* hist, uint32_t* chunkSuf,
                                             volatile uint32_t* outBin,
                                             volatile uint32_t* outRank, uint32_t K) {
  int tid = threadIdx.x;
  if (tid < 512) {
    int base = tid * 16;
    uint32_t csum = 0;
#pragma unroll
    for (int k = 0; k < 16; k++) csum += hist[base + k];
    chunkSuf[tid] = csum;
  }
  __syncthreads();
  if (tid < 64) {
    uint32_t cs[8];
    uint32_t g = 0;
#pragma unroll
    for (int m = 0; m < 8; m++) { cs[m] = chunkSuf[tid * 8 + m]; g += cs[m]; }
    uint32_t v = g;
#pragma unroll
    for (int off = 1; off < 64; off <<= 1) {
      uint32_t u = __shfl_down(v, off);
      if (tid + off < 64) v += u;
    }
    uint32_t run = v - g;
    for (int m = 7; m >= 0; m--) {
      chunkSuf[tid * 8 + m] = run;
      run += cs[m];
    }
  }
  __syncthreads();
  if (tid < 512) {
    int base = tid * 16;
    uint32_t run = chunkSuf[tid];
    for (int k = 15; k >= 0; k--) {
      uint32_t h = hist[base + k];
      if (run < K && run + h >= K) {
        *outBin = (uint32_t)(base + k);
        *outRank = K - run;
      }
      run += h;
    }
  }
  __syncthreads();
}

// Sampled histogram: rows r ≡ 0 (mod 8). Each thread: 8 sampled rows x 4 cols.
__device__ __forceinline__ void sample_pass(const float* __restrict__ x,
                                            uint32_t* hist) {
  int tid = threadIdx.x;
  int lane_c = (tid & 127) << 2;
  int r0 = (tid >> 7) << 6;
  const bool haveE = lane_c + 4 < W;
  const float* xc = x + lane_c;
  float4 uA[2], uB[2];
  float fA[2], fB[2];
#define LDS2(k, buf)                                      \
  {                                                       \
    const float* rp = xc + (size_t)(r0 + 8 * (k)) * W;    \
    uA[buf] = *(const float4*)rp;                         \
    fA[buf] = haveE ? rp[4] : 0.f;                        \
    uB[buf] = *(const float4*)(rp + W);                   \
    fB[buf] = haveE ? rp[W + 4] : 0.f;                    \
  }
  LDS2(0, 0)
  for (int k = 0; k < 8; ++k) {
    int cb = k & 1;
    if (k < 7) LDS2(k + 1, cb ^ 1)
    float a[5] = {uA[cb].x, uA[cb].y, uA[cb].z, uA[cb].w, fA[cb]};
    float c[5] = {uB[cb].x, uB[cb].y, uB[cb].z, uB[cb].w, fB[cb]};
#pragma unroll
    for (int j = 0; j < 4; j++) {
      float g0 = a[j] - c[j + 1];
      float g1 = a[j + 1] - c[j];
      float msq = fmaf(g0, g0, fmaf(g1, g1, 1e-12f));
      atomicAdd(&hist[__float_as_uint(msq) >> 19], 1u);
    }
  }
#undef LDS2
}

#define LDR(r, v, e)                                  \
  {                                                   \
    if ((r) < H) {                                    \
      const float* rp = xc + (size_t)(r) * W;         \
      v = *(const float4*)rp;                         \
      e = haveE ? rp[4] : 0.f;                        \
    } else { v = f4zero(); e = 0.f; }                 \
  }

// Histogram-free full pass: register-count values above the bracket, collect
// bracket candidates via wave-aggregated append. No per-value LDS atomics.
__device__ __forceinline__ void count_pass(const float* __restrict__ x,
                                           uint32_t* cand, uint32_t* sCnt,
                                           uint32_t* sAbove, uint32_t loBits,
                                           uint32_t hiBits) {
  int tid = threadIdx.x;
  int lane = tid & 63;
  int lane_c = (tid & 127) << 2;
  int r0 = (tid >> 7) << 6;
  const bool haveE = lane_c + 4 < W;
  const float* xc = x + lane_c;
  uint32_t above = 0;

  float4 vA, vB, vC, vD;
  float eA = 0.f, eB = 0.f, eC = 0.f, eD = 0.f;
  LDR(r0, vA, eA)
  LDR(r0 + 1, vB, eB)
  LDR(r0 + 2, vC, eC)
  for (int it = 0; it < 64; ++it) {
    int r = r0 + it;
    if (it < 62) { LDR(r + 3, vD, eD) } else { vD = f4zero(); eD = 0.f; }
    float a[5] = {vA.x, vA.y, vA.z, vA.w, eA};
    float c[5] = {vB.x, vB.y, vB.z, vB.w, eB};
#pragma unroll
    for (int j = 0; j < 4; j++) {
      float g0 = a[j] - c[j + 1];
      float g1 = a[j + 1] - c[j];
      float msq = fmaf(g0, g0, fmaf(g1, g1, 1e-12f));
      uint32_t bits = __float_as_uint(msq);
      above += (bits >= hiBits) ? 1u : 0u;
      bool w = (bits >= loBits) && (bits < hiBits);
      unsigned long long mk = __ballot(w);
      if (mk) {  // wave-uniform branch; rare (~4% of values in bracket)
        uint32_t base = 0;
        int leader = __ffsll(mk) - 1;
        uint32_t pre = (uint32_t)__popcll(mk & ((1ull << lane) - 1ull));
        if (lane == leader) base = atomicAdd(sCnt, (uint32_t)__popcll(mk));
        base = (uint32_t)__shfl((int)base, leader);
        if (w) {
          uint32_t idx = base + pre;
          if (idx < CAP) cand[idx] = bits;
        }
      }
    }
    vA = vB; eA = eB; vB = vC; eB = eC; vC = vD; eC = eD;
  }
  for (int off = 32; off; off >>= 1) above += __shfl_down(above, off);
  if (lane == 0) atomicAdd(sAbove, above);
}

// Fallback path (rare). HIST=1: full LDS histogram (no collect when lo is
// impossible). HIST=0: collect bin==lo only.
template <int HIST>
__device__ __forceinline__ void full_pass(const float* __restrict__ x,
                                          uint32_t* hist, uint32_t* cand,
                                          uint32_t* sCnt, uint32_t lo,
                                          uint32_t span) {
  int tid = threadIdx.x;
  int lane_c = (tid & 127) << 2;
  int r0 = (tid >> 7) << 6;
  const bool haveE = lane_c + 4 < W;
  const float* xc = x + lane_c;

  float4 vA, vB, vC, vD;
  float eA = 0.f, eB = 0.f, eC = 0.f, eD = 0.f;
  LDR(r0, vA, eA)
  LDR(r0 + 1, vB, eB)
  LDR(r0 + 2, vC, eC)
  for (int it = 0; it < 64; ++it) {
    int r = r0 + it;
    if (it < 62) { LDR(r + 3, vD, eD) } else { vD = f4zero(); eD = 0.f; }
    float a[5] = {vA.x, vA.y, vA.z, vA.w, eA};
    float c[5] = {vB.x, vB.y, vB.z, vB.w, eB};
#pragma unroll
    for (int j = 0; j < 4; j++) {
      float g0 = a[j] - c[j + 1];
      float g1 = a[j + 1] - c[j];
      float msq = fmaf(g0, g0, fmaf(g1, g1, 1e-12f));
      uint32_t bits = __float_as_uint(msq);
      uint32_t bin = bits >> 19;
      if (HIST) atomicAdd(&hist[bin], 1u);
      if (bin - lo <= span) {
        uint32_t idx = atomicAdd(sCnt, 1u);
        if (idx < CAP) cand[idx] = bits;
      }
    }
    vA = vB; eA = eB; vB = vC; eB = eC; vC = vD; eC = eD;
  }
}
#undef LDR

// One block per (tensor, image). Sampled pilot brackets the threshold bin;
// the single full pass does NO histogram atomics: register count-above +
// wave-aggregated bracket collect. Exact rank-AX threshold always.
__global__ __launch_bounds__(1024) void selectKernel(const float* __restrict__ target,
                                                     const float* __restrict__ pred,
                                                     float* __restrict__ thr,
                                                     double* __restrict__ sum) {
  extern __shared__ uint32_t smem[];
  uint32_t* hist = smem;                           // NB
  uint32_t* cand = smem + NB;                      // CAP
  uint32_t* chunkSuf = smem + NB + CAP;            // 512
  volatile uint32_t* sBin = smem + NB + CAP + 512;
  volatile uint32_t* sRank = smem + NB + CAP + 513;
  uint32_t* sCnt = smem + NB + CAP + 514;
  uint32_t* sAbove = smem + NB + CAP + 515;

  int tid = threadIdx.x;
  int b = blockIdx.x;
  if (b == 0 && tid == 0) *sum = 0.0;  // folded initKernel
  int img = b & 127;
  const float* __restrict__ x = ((b >> 7) ? pred : target) + (size_t)img * HW;

  for (int i = tid; i < NB; i += 1024) hist[i] = 0;
  if (tid == 0) { *sCnt = 0; *sAbove = 0; }
  __syncthreads();

  // Phase A: sampled pilot -> bracket [bLo, bHi]
  sample_pass(x, hist);
  __syncthreads();
  block_select(hist, chunkSuf, sBin, sRank, KS - KM);
  uint32_t bHi = *sBin;
  block_select(hist, chunkSuf, sBin, sRank, KS + KM);
  uint32_t bLo = *sBin;
  __syncthreads();

  // Phase B: single full pass, histogram-free
  uint32_t loBits = bLo << 19;
  uint32_t hiBits = (bHi >= 8191u) ? 0xFFFFFFFFu : ((bHi + 1u) << 19);
  count_pass(x, cand, sCnt, sAbove, loBits, hiBits);
  __syncthreads();
  uint32_t cnt = *sCnt;
  uint32_t above = *sAbove;
  __syncthreads();

  uint32_t b0, K1;
  bool ok = (above < AX) && ((AX - above) <= cnt) && (cnt <= CAP);
  if (ok) {
    // Small histogram over candidates only (~5K atomics)
    for (int i = tid; i < NB; i += 1024) hist[i] = 0;
    __syncthreads();
    for (uint32_t j = tid; j < cnt; j += 1024)
      atomicAdd(&hist[cand[j] >> 19], 1u);
    __syncthreads();
    block_select(hist, chunkSuf, sBin, sRank, AX - above);
    b0 = *sBin;
    K1 = *sRank;
    __syncthreads();
  } else {
    // Fallback: classic 2-pass exact path
    for (int i = tid; i < NB; i += 1024) hist[i] = 0;
    __syncthreads();
    full_pass<1>(x, hist, cand, sCnt, 0xFFFFFFFFu, 0u);  // hist only
    __syncthreads();
    block_select(hist, chunkSuf, sBin, sRank, AX);
    b0 = *sBin;
    K1 = *sRank;
    if (tid == 0) *sCnt = 0;
    __syncthreads();
    full_pass<0>(x, hist, cand, sCnt, b0, 0u);  // collect bin==b0
    __syncthreads();
    cnt = *sCnt;
    if (cnt > CAP) cnt = CAP;
    __syncthreads();
  }

  // Mini-round 1: next 13 bits (filter to bin b0)
  for (int i = tid; i < NB; i += 1024) hist[i] = 0;
  __syncthreads();
  for (uint32_t j = tid; j < cnt; j += 1024) {
    uint32_t bits = cand[j];
    if ((bits >> 19) == b0) atomicAdd(&hist[(bits >> 6) & 0x1FFFu], 1u);
  }
  __syncthreads();
  block_select(hist, chunkSuf, sBin, sRank, K1);
  uint32_t b1 = *sBin;
  uint32_t K2 = *sRank;
  __syncthreads();

  // Mini-round 2: last 6 bits
  for (int i = tid; i < NB; i += 1024) hist[i] = 0;
  __syncthreads();
  for (uint32_t j = tid; j < cnt; j += 1024) {
    uint32_t bits = cand[j];
    if ((bits >> 19) == b0 && ((bits >> 6) & 0x1FFFu) == b1)
      atomicAdd(&hist[bits & 63u], 1u);
  }
  __syncthreads();
  block_select(hist, chunkSuf, sBin, sRank, K2);
  if (tid == 0) {
    uint32_t tb = (b0 << 19) | (b1 << 6) | *sBin;
    thr[b] = __uint_as_float(tb);  // SQUARED threshold bits
  }
}

// Per-position sequential carry over images. Thread = 2 cols (float2) x 1 row;
// col c+2 via scalar load (L1 hit, no shfl). Depth-2 image pipeline.
// 512 blocks x 256 thr = 2 blocks/CU = 8 waves/CU; ~48B/thread in flight.
// XCD swizzle: 64 contiguous rows per XCD.
__global__ __launch_bounds__(256) void scanKernel(const float* __restrict__ target,
                                                  const float* __restrict__ pred,
                                                  const float* __restrict__ thr,
                                                  double* __restrict__ sum) {
  __shared__ float sT[NIMG], sP[NIMG];
  __shared__ float ws4[4];
  int tid = threadIdx.x;
  if (tid < NIMG) sT[tid] = thr[tid];
  else if (tid < 2 * NIMG) sP[tid - NIMG] = thr[tid];
  __syncthreads();
  int b = blockIdx.x;
  int r = ((b & 7) << 6) + (b >> 3);  // XCD-contiguous rows
  int c = tid << 1;
  const bool haveB = r + 1 < H;  // block-uniform
  const bool haveE = c + 2 < W;  // only false for tid==255
  size_t offA = (size_t)r * W + c;
  size_t offB = offA + W;

  float2 tA[2], tB[2], pA[2], pB[2];
  float tAe[2], tBe[2], pAe[2], pBe[2];

#define LOADI(i, buf)                                                  \
  {                                                                    \
    const float* xt = target + (size_t)(i) * HW;                       \
    const float* xp = pred + (size_t)(i) * HW;                         \
    tA[buf] = *(const float2*)(xt + offA);                             \
    pA[buf] = *(const float2*)(xp + offA);                             \
    tB[buf] = haveB ? *(const float2*)(xt + offB) : make_float2(0.f, 0.f); \
    pB[buf] = haveB ? *(const float2*)(xp + offB) : make_float2(0.f, 0.f); \
    tAe[buf] = haveE ? xt[offA + 2] : 0.f;                             \
    pAe[buf] = haveE ? xp[offA + 2] : 0.f;                             \
    tBe[buf] = (haveE && haveB) ? xt[offB + 2] : 0.f;                  \
    pBe[buf] = (haveE && haveB) ? xp[offB + 2] : 0.f;                  \
  }

  float etf0 = 0.f, etf1 = 0.f, epf0 = 0.f, epf1 = 0.f, acc = 0.f;
  LOADI(0, 0)
#pragma unroll 2
  for (int i = 0; i < NIMG; ++i) {
    int cb = i & 1;
    if (i + 1 < NIMG) LOADI(i + 1, cb ^ 1)
    float tsqT = sT[i], tsqP = sP[i];
    // position (r, c)
    float g0 = tA[cb].x - tB[cb].y;
    float g1 = tA[cb].y - tB[cb].x;
    float m = fmaf(g0, g0, fmaf(g1, g1, 1e-12f));
    if (m >= tsqT) etf0 = sqrtf(m);
    g0 = pA[cb].x - pB[cb].y;
    g1 = pA[cb].y - pB[cb].x;
    m = fmaf(g0, g0, fmaf(g1, g1, 1e-12f));
    if (m >= tsqP) epf0 = sqrtf(m);
    acc += fabsf((etf0 - epf0) / (etf0 + epf0 + 1e-5f));
    // position (r, c+1)
    g0 = tA[cb].y - tBe[cb];
    g1 = tAe[cb] - tB[cb].y;
    m = fmaf(g0, g0, fmaf(g1, g1, 1e-12f));
    if (m >= tsqT) etf1 = sqrtf(m);
    g0 = pA[cb].y - pBe[cb];
    g1 = pAe[cb] - pB[cb].y;
    m = fmaf(g0, g0, fmaf(g1, g1, 1e-12f));
    if (m >= tsqP) epf1 = sqrtf(m);
    acc += fabsf((etf1 - epf1) / (etf1 + epf1 + 1e-5f));
  }
#undef LOADI

  for (int off = 32; off; off >>= 1) acc += __shfl_down(acc, off);
  if ((tid & 63) == 0) ws4[tid >> 6] = acc;
  __syncthreads();
  if (tid == 0) {
    double s = (double)ws4[0] + (double)ws4[1] + (double)ws4[2] + (double)ws4[3];
    atomicAdd(sum, s);
  }
}

__global__ void finalKernel(const double* __restrict__ sum,
                            const float* __restrict__ alpha,
                            float* __restrict__ out) {
  out[0] = (float)((double)alpha[0] * (sum[0] / (double)((double)NIMG * (double)HW)));
}

extern "C" void kernel_launch(void* const* d_in, const int* in_sizes, int n_in,
                              void* d_out, int out_size, void* d_ws, size_t ws_size,
                              hipStream_t stream) {
  const float* pred = (const float*)d_in[0];    // predictions [16,8,512,512]
  const float* target = (const float*)d_in[1];  // target      [16,8,512,512]
  const float* alpha = (const float*)d_in[2];   // scalar
  // d_in[3] = Roberts kernels (fixed values, hardcoded)

  double* d_sum = (double*)d_ws;
  float* d_thr = (float*)((char*)d_ws + 64);  // 256 floats (squared-threshold bits)

  static int attrSet = 0;
  if (!attrSet) {
    hipFuncSetAttribute(reinterpret_cast<const void*>(&selectKernel),
                        hipFuncAttributeMaxDynamicSharedMemorySize, SMEM_BYTES);
    attrSet = 1;
  }

  selectKernel<<<256, 1024, SMEM_BYTES, stream>>>(target, pred, d_thr, d_sum);
  scanKernel<<<512, 256, 0, stream>>>(target, pred, d_thr, d_sum);
  finalKernel<<<1, 1, 0, stream>>>(d_sum, alpha, (float*)d_out);
}